// Round 1
// 120.505 us; speedup vs baseline: 1.0018x; 1.0018x over previous
//
#include <hip/hip_runtime.h>
#include <math.h>

#define N_MELS   128
#define N_FFT    2048
#define HOP      512
#define BATCH    8
#define S_LEN    661500
#define CH       2
#define T_FRAMES 1292            // 1 + S_LEN/HOP
#define NBINS    1025            // 1 + N_FFT/2

#define ANG 0.003067961575771282f   // 2*pi/2048

// d_ws layout (byte offsets)
#define WS_WIN     0        // float[2048]   hann window
#define WS_TW      8192     // float2[2048]  W_2048^j
#define WS_WBEG    24576    // int[128]      4-aligned start bin per mel
#define WS_WTAB    25600    // float[128*64] dense zero-padded mel weights

// pw planes: [h*PW_FR + c*PW_OFF + f]. Strides chosen so the (m,h) lane
// pairs in the mel loop land on DISJOINT bank groups:
//   PW_FR  = 2120 ≡ 8  (mod 32 banks), PW_OFF = 1060 ≡ 4 (mod 32 banks).
// Both are multiples of 4 so float4 reads stay 16B-aligned.
// Max float index = 2120 + 1060 + 1055 = 4235 < 4608 (buffer floats).
#define PW_OFF   1060       // channel-plane stride (floats)
#define PW_FR    2120       // frame-plane stride (floats)

// Full padded buffer: element e in [0,2048) lives at Z2[e + 2*(e>>4)].
#define ZN 2304             // float2 count = 2048 + 2*128 -> 18432 B

__device__ __forceinline__ float2 cadd(float2 a, float2 b){ return make_float2(a.x+b.x, a.y+b.y); }
__device__ __forceinline__ float2 csub(float2 a, float2 b){ return make_float2(a.x-b.x, a.y-b.y); }
__device__ __forceinline__ float2 cmul(float2 a, float2 b){ return make_float2(a.x*b.x - a.y*b.y, a.x*b.y + a.y*b.x); }
__device__ __forceinline__ float2 cnegi(float2 z){ return make_float2(z.y, -z.x); }   // -i*z

// radix-8 DIF butterfly: b[k] = sum_j a[j] * W8^{jk}, W8 = exp(-i*pi/4)
__device__ __forceinline__ void bfly8(const float2* a, float2* b) {
    const float C = 0.70710678118654752f;
    float2 e0=cadd(a[0],a[4]), e1=cadd(a[1],a[5]), e2=cadd(a[2],a[6]), e3=cadd(a[3],a[7]);
    float2 o0=csub(a[0],a[4]), o1=csub(a[1],a[5]), o2=csub(a[2],a[6]), o3=csub(a[3],a[7]);
    float2 t1 = make_float2(C*(o1.x+o1.y), C*(o1.y-o1.x));      // o1*W8^1
    float2 t2 = make_float2(o2.y, -o2.x);                        // o2*W8^2 (-i)
    float2 t3 = make_float2(C*(o3.y-o3.x), -C*(o3.x+o3.y));      // o3*W8^3
    {
        float2 s0=cadd(e0,e2), d0=csub(e0,e2);
        float2 s1=cadd(e1,e3), d1=csub(e1,e3);
        b[0]=cadd(s0,s1); b[4]=csub(s0,s1);
        b[2]=cadd(d0,cnegi(d1)); b[6]=csub(d0,cnegi(d1));
    }
    {
        float2 s0=cadd(o0,t2), d0=csub(o0,t2);
        float2 s1=cadd(t1,t3), d1=csub(t1,t3);
        b[1]=cadd(s0,s1); b[5]=csub(s0,s1);
        b[3]=cadd(d0,cnegi(d1)); b[7]=csub(d0,cnegi(d1));
    }
}

// Both frames: bfly8 + shared incremental twiddle chain, results back into rA/rB.
__device__ __forceinline__ void stage_pair(float2* rA, float2* rB, float2 w1) {
    float2 bqA[8], bqB[8];
    bfly8(rA, bqA);
    bfly8(rB, bqB);
    rA[0] = bqA[0]; rB[0] = bqB[0];
    float2 wk = w1;
    #pragma unroll
    for (int k = 1; k < 8; ++k) {
        rA[k] = cmul(wk, bqA[k]);
        rB[k] = cmul(wk, bqB[k]);
        wk = cmul(wk, w1);
    }
}

// stage-4 radix-4 (s=512, twiddle-free) butterfly
__device__ __forceinline__ void bf4(const float2* I, float2* O) {
    float2 apc=cadd(I[0],I[2]), amc=csub(I[0],I[2]);
    float2 bpd=cadd(I[1],I[3]), bmd=csub(I[1],I[3]);
    O[0]=cadd(apc,bpd); O[1]=cadd(amc,cnegi(bmd));
    O[2]=csub(apc,bpd); O[3]=csub(amc,cnegi(bmd));
}

// two-channel untangle: (|A|^2, |B|^2) for Zf, Zm = Z[N-f]
__device__ __forceinline__ float2 upair(float2 Zf, float2 Zm) {
    float br = Zm.x, bi = -Zm.y;
    float e0 = Zf.x + br, e1 = Zf.y + bi;
    float o0 = Zf.y - bi, o1 = Zf.x - br;
    return make_float2(0.25f*(e0*e0 + e1*e1), 0.25f*(o0*o0 + o1*o1));
}

// --- setup: blocks 0..7 build tables; blocks 8..135: mel weight rows ---
__global__ __launch_bounds__(256) void setup_kernel(
        const float* __restrict__ fb, float* __restrict__ ws) {
    int blk = blockIdx.x;
    if (blk < 8) {
        int i = blk * 256 + threadIdx.x;
        float*  win = ws;
        float2* tw  = (float2*)((char*)ws + WS_TW);
        win[i] = 0.5f - 0.5f * cosf(ANG * (float)i);
        float sn, cs; sincosf(-ANG * (float)i, &sn, &cs);
        tw[i] = make_float2(cs, sn);
    } else {
        int m = blk - 8;
        int lane = threadIdx.x;
        if (lane < 64) {
            int*   wbeg = (int*)((char*)ws + WS_WBEG);
            float* wtab = (float*)((char*)ws + WS_WTAB);
            const float* row = fb + m * NBINS;
            int s = NBINS;
            for (int f = lane; f < NBINS; f += 64)
                if (row[f] != 0.0f && f < s) s = f;
            #pragma unroll
            for (int o = 32; o; o >>= 1) s = min(s, __shfl_xor(s, o));
            int a0 = s & ~3;              // 4-aligned start; slaney span<=54+3<64
            if (a0 > NBINS - 1) a0 = (NBINS - 1) & ~3;
            if (lane == 0) wbeg[m] = a0;
            int f = a0 + lane;
            wtab[(m << 6) + lane] = (f < NBINS) ? row[f] : 0.0f;
        }
    }
}

// --- main: 2 frames per block; full-buffer exchange, frames alternate ---
// launch_bounds(256, 8): VGPR=40 baseline leaves room; 18432B LDS allows
// 8 blocks/CU (147KB of 160KB). Baseline was pinned at 16 waves (48.6%).
__global__ __launch_bounds__(256, 8) void mel_spec_kernel(
        const float* __restrict__ x, const float* __restrict__ fb,
        const float* __restrict__ ws, float* __restrict__ out) {
    __shared__ float4 Zq[ZN/2];          // 18432 B, one full padded buffer
    float2* Z2  = (float2*)Zq;
    float*  pwb = (float*)Zq;            // pw planes: [h*2120 + c*1060 + f]

    const float*  win  = ws;
    const float2* tw   = (const float2*)((const char*)ws + WS_TW);
    const int*    wbeg = (const int*)((const char*)ws + WS_WBEG);
    const float*  wtab = (const float*)((const char*)ws + WS_WTAB);

    const int tid = threadIdx.x;
    const int bid = blockIdx.x;
    const int b   = bid & 7;              // XCD-contiguous: one batch item per XCD
    const int t0  = (bid >> 3) * 2;       // frames t0, t0+1

    const float2* xb = (const float2*)x + (size_t)b * S_LEN;
    const int tbA = t0*HOP - (N_FFT/2);
    const int tbB = tbA + HOP;

    float2 rA[8], rB[8];
    const int rb = tid + 2*(tid>>4);      // OFFE(tid); +288 per 256 elements

    // ---- Input: frames overlap by 1536 samples (HOP=512=2*256), so
    // frame-B element (tid,k) == frame-A element (tid,k+2). Fast path loads
    // 10 float2/thread instead of 16.
    if (tbA >= 0 && tbB + (N_FFT - 1) < S_LEN) {
        float2 v[10];
        #pragma unroll
        for (int k = 0; k < 10; ++k) v[k] = xb[tbA + tid + 256*k];
        #pragma unroll
        for (int k = 0; k < 8; ++k) {
            float w = win[tid + 256*k];
            rA[k] = make_float2(v[k].x*w,   v[k].y*w);
            rB[k] = make_float2(v[k+2].x*w, v[k+2].y*w);
        }
    } else {
        #pragma unroll
        for (int k = 0; k < 8; ++k) {
            int n  = tid + 256*k;
            float w = win[n];
            int sA = tbA + n;
            if (sA < 0) sA = -sA; else if (sA >= S_LEN) sA = 2*S_LEN - 2 - sA;
            float2 vA = xb[sA];
            rA[k] = make_float2(vA.x*w, vA.y*w);
            int sB = tbB + n;
            if (sB < 0) sB = -sB; else if (sB >= S_LEN) sB = 2*S_LEN - 2 - sB;
            float2 vB = xb[sB];
            rB[k] = make_float2(vB.x*w, vB.y*w);
        }
    }

    // ======== Stage 1: radix-8, s=1. Outputs e = 8*tid + k (b128 writes).
    stage_pair(rA, rB, tw[tid]);
    {
        const int f4 = 4*tid + (tid>>1);          // float4 index of OFFE(8*tid)/2
        #pragma unroll
        for (int j = 0; j < 4; ++j)
            Zq[f4+j] = make_float4(rA[2*j].x, rA[2*j].y, rA[2*j+1].x, rA[2*j+1].y);
        __syncthreads();
        #pragma unroll
        for (int k = 0; k < 8; ++k) rA[k] = Z2[rb + 288*k];
        __syncthreads();
        #pragma unroll
        for (int j = 0; j < 4; ++j)
            Zq[f4+j] = make_float4(rB[2*j].x, rB[2*j].y, rB[2*j+1].x, rB[2*j+1].y);
        __syncthreads();
        #pragma unroll
        for (int k = 0; k < 8; ++k) rB[k] = Z2[rb + 288*k];
        __syncthreads();
    }

    // ======== Stage 2: radix-8, s=8. Outputs e = q + 64a + 8k.
    stage_pair(rA, rB, tw[tid & ~7]);
    {
        const int base = (tid & 7) + 72*(tid >> 3);
        #pragma unroll
        for (int k = 0; k < 8; ++k) Z2[base + 8*k + 2*(k>>1)] = rA[k];
        __syncthreads();
        #pragma unroll
        for (int k = 0; k < 8; ++k) rA[k] = Z2[rb + 288*k];
        __syncthreads();
        #pragma unroll
        for (int k = 0; k < 8; ++k) Z2[base + 8*k + 2*(k>>1)] = rB[k];
        __syncthreads();
        #pragma unroll
        for (int k = 0; k < 8; ++k) rB[k] = Z2[rb + 288*k];
        __syncthreads();
    }

    // ======== Stage 3: radix-8, s=64. Outputs e = q + 512a + 64k.
    stage_pair(rA, rB, tw[tid & ~63]);
    // Stage-4 butterfly pair: b1 = tid, b2 = 512-tid (tid=0 -> {0,256}).
    const int b2  = (tid == 0) ? 256 : 512 - tid;
    const int rb2 = b2 + 2*(b2>>4);
    float2 A1[4], A2[4], B1[4], B2[4];
    {
        const int q = tid & 63;
        const int base = q + 2*(q>>4) + 576*(tid >> 6);
        #pragma unroll
        for (int k = 0; k < 8; ++k) Z2[base + 72*k] = rA[k];
        __syncthreads();
        #pragma unroll
        for (int k = 0; k < 4; ++k) { A1[k] = Z2[rb + 576*k]; A2[k] = Z2[rb2 + 576*k]; }
        __syncthreads();
        #pragma unroll
        for (int k = 0; k < 8; ++k) Z2[base + 72*k] = rB[k];
        __syncthreads();
        #pragma unroll
        for (int k = 0; k < 4; ++k) { B1[k] = Z2[rb + 576*k]; B2[k] = Z2[rb2 + 576*k]; }
        __syncthreads();
    }

    // ======== Stage 4 + untangle, straight-line per frame (registers only,
    // then pw-plane writes into Zq; all Zq reads fenced above).
    // Also zero the 35-float gap [1025,1060) after each plane so the mel
    // loop's tail reads (a0 up to 972 -> f up to 1035) hit exact zeros,
    // not stale FFT leftovers.
    if (tid < 140) {
        int p = tid / 35;
        int o = tid - p * 35;
        pwb[(p>>1)*PW_FR + (p&1)*PW_OFF + 1025 + o] = 0.0f;
    }
    {
        float2 O1[4], O2[4];
        bf4(A1, O1); bf4(A2, O2);
        float* pwf = pwb;                          // frame A planes (h=0)
        if (tid == 0) {
            float2 p;
            p = upair(O1[0], O1[0]); pwf[0]    = p.x; pwf[PW_OFF+0]    = p.y;
            p = upair(O1[1], O1[3]); pwf[512]  = p.x; pwf[PW_OFF+512]  = p.y;
            p = upair(O1[2], O1[2]); pwf[1024] = p.x; pwf[PW_OFF+1024] = p.y;
            p = upair(O2[0], O2[3]); pwf[256]  = p.x; pwf[PW_OFF+256]  = p.y;
            p = upair(O2[1], O2[2]); pwf[768]  = p.x; pwf[PW_OFF+768]  = p.y;
        } else {
            float2 p;
            p = upair(O1[0], O2[3]); pwf[tid]      = p.x; pwf[PW_OFF+tid]      = p.y;
            p = upair(O1[1], O2[2]); pwf[tid+512]  = p.x; pwf[PW_OFF+tid+512]  = p.y;
            p = upair(O2[0], O1[3]); pwf[512-tid]  = p.x; pwf[PW_OFF+512-tid]  = p.y;
            p = upair(O2[1], O1[2]); pwf[1024-tid] = p.x; pwf[PW_OFF+1024-tid] = p.y;
        }
    }
    {
        float2 O1[4], O2[4];
        bf4(B1, O1); bf4(B2, O2);
        float* pwf = pwb + PW_FR;                  // frame B planes (h=1)
        if (tid == 0) {
            float2 p;
            p = upair(O1[0], O1[0]); pwf[0]    = p.x; pwf[PW_OFF+0]    = p.y;
            p = upair(O1[1], O1[3]); pwf[512]  = p.x; pwf[PW_OFF+512]  = p.y;
            p = upair(O1[2], O1[2]); pwf[1024] = p.x; pwf[PW_OFF+1024] = p.y;
            p = upair(O2[0], O2[3]); pwf[256]  = p.x; pwf[PW_OFF+256]  = p.y;
            p = upair(O2[1], O2[2]); pwf[768]  = p.x; pwf[PW_OFF+768]  = p.y;
        } else {
            float2 p;
            p = upair(O1[0], O2[3]); pwf[tid]      = p.x; pwf[PW_OFF+tid]      = p.y;
            p = upair(O1[1], O2[2]); pwf[tid+512]  = p.x; pwf[PW_OFF+tid+512]  = p.y;
            p = upair(O2[0], O1[3]); pwf[512-tid]  = p.x; pwf[PW_OFF+512-tid]  = p.y;
            p = upair(O2[1], O1[2]); pwf[1024-tid] = p.x; pwf[PW_OFF+1024-tid] = p.y;
        }
    }
    __syncthreads();

    // ======== Mel projection: thread = (m, frame h); both channels -> float2 out.
    // PW_FR % 32 == 8 and PW_OFF % 32 == 4, so the (m,h=0)/(m,h=1) lane pair
    // reads disjoint 4-bank groups (baseline: identical groups, guaranteed
    // 2-way conflict on every ds_read_b128 -> the 6.6M conflict cycles).
    {
        int m = tid >> 1;
        int h = tid & 1;                       // frame t0+h
        int a0 = wbeg[m];
        const float4* wt4 = (const float4*)(wtab + (m << 6));
        const float*  p0  = pwb + h*PW_FR + a0;            // channel 0 plane
        const float*  p1  = pwb + h*PW_FR + PW_OFF + a0;   // channel 1 plane
        float acc0 = 0.0f, acc1 = 0.0f;
        #pragma unroll
        for (int j = 0; j < 16; ++j) {
            float4 w4 = wt4[j];
            float4 q0 = *(const float4*)(p0 + 4*j);
            float4 q1 = *(const float4*)(p1 + 4*j);
            acc0 += w4.x*q0.x + w4.y*q0.y + w4.z*q0.z + w4.w*q0.w;
            acc1 += w4.x*q1.x + w4.y*q1.y + w4.z*q1.z + w4.w*q1.w;
        }
        size_t base = (((size_t)b * N_MELS + m) * T_FRAMES + t0 + h) * CH;
        *(float2*)(out + base) = make_float2(acc0, acc1);
    }
}

extern "C" void kernel_launch(void* const* d_in, const int* in_sizes, int n_in,
                              void* d_out, int out_size, void* d_ws, size_t ws_size,
                              hipStream_t stream) {
    const float* x  = (const float*)d_in[0];
    const float* fb = (const float*)d_in[1];
    float* out = (float*)d_out;
    float* ws  = (float*)d_ws;

    setup_kernel<<<8 + N_MELS, 256, 0, stream>>>(fb, ws);
    mel_spec_kernel<<<BATCH * (T_FRAMES/2), 256, 0, stream>>>(x, fb, ws, out);
}